// Round 15
// baseline (352.373 us; speedup 1.0000x reference)
//
#include <hip/hip_runtime.h>
#include <hip/hip_bf16.h>
#include <cmath>

// LinearAttention: x[4,4096,1024] fp32 -> qkv -> elu+1 linear attention (16 heads, d=64) -> out proj.
// I/O fp32; internal bf16 MFMA w/ fp32 accum.
// Round 13 (resubmit x2; prior benches were GPUAcquisitionTimeout, kernel never ran):
//   - REVERT T1 XCD swizzle (R12 post-mortem: FETCH 145->220MB, gemm +6us -- mapping destroyed
//     the n-fastest sweep's B-panel locality).
//   - MODE0 KT/VT stores coalesced via LDS transpose. Old path: 8B bf16x4 stores at 8KB stride
//     (per-lane [hh][d] rows) -> sub-line RFO + write-amp: WRITE 145MB vs 96MB logical, FETCH
//     145MB vs 38MB inputs. New: 128x128 tile bounced through LDS [col][tok] (pitch 132; As/Bs
//     aliased into one 33KB buffer), then 128 rows x 256B contiguous cooperative stores.
//   - kv_partial stays barrier-free reg-MFMA (ksp=16); attn_out reduces 16 partials; cvt3 merged.
// Pipeline:
//   0) cvt3: x->xb, w_qkv->wqkvb, w_out->woutb (bf16)
//   1) gemm_bt<0>: qkv = xb @ wqkvb^T; epilogue q->feat*scale->Q[b,h,n,d], k->KT[b,h,d,n], v->VT
//   2) kv_partial: kvp[hh][ksp][e][d] = sum_n v[n,e] k[n,d]; ksp[hh][ksp][d] = sum_n k[n,d] (ksp=16)
//   3) attn_out: preamble reduces kvp/ksp -> LDS; att = (q @ kv) / (q . ksum + eps)
//   4) gemm_bt<1>: y = att @ woutb^T + b_out (fp32 out)

typedef __bf16 bf16_t;
typedef __attribute__((ext_vector_type(8))) __bf16 bf16x8;
typedef __attribute__((ext_vector_type(4))) __bf16 bf16x4;
typedef __attribute__((ext_vector_type(4))) float f32x4;
typedef __attribute__((ext_vector_type(8))) float f32x8;

#define MFMA16(a, b, c) __builtin_amdgcn_mfma_f32_16x16x32_bf16((a), (b), (c), 0, 0, 0)

#define LDS_PITCH 72   // padded pitch for attn_out kvT
#define TP_PITCH 132   // padded pitch for the MODE0 KT/VT transpose bounce (128 + 4)

__device__ __forceinline__ f32x4 zf4() { f32x4 z; z[0] = 0.f; z[1] = 0.f; z[2] = 0.f; z[3] = 0.f; return z; }

__device__ __forceinline__ float feat(float x) { return x > 0.f ? x + 1.f : expf(x); }

// ---------------- async staging (GEMM path) ----------------
__device__ __forceinline__ void gld_lds16(const bf16_t* src, bf16_t* dst)
{
    __builtin_amdgcn_global_load_lds(
        (__attribute__((address_space(1))) void*)const_cast<bf16_t*>(src),
        (__attribute__((address_space(3))) void*)dst, 16, 0, 0);
}

// Stage NR x 64 bf16 tile (row stride ld) into LDS, XOR-swizzled, via global_load_lds.
// LDS granule (row, sw) holds global granule (row, sw^(row&7)); readers apply the same XOR.
template <int NR>
__device__ __forceinline__ void stage_async(const bf16_t* g, int ld, bf16_t* lds, int tid)
{
    const int w = tid >> 6, l = tid & 63;
    constexpr int CALLS = NR >> 5;  // per-wave calls; each call = 64 granules = 8 rows
#pragma unroll
    for (int p = 0; p < CALLS; ++p) {
        const int chunk = w * CALLS + p;         // wave-uniform
        const int gidx = chunk * 64 + l;
        const int row = gidx >> 3;
        const int cp = gidx & 7;
        const int c = cp ^ (row & 7);
        gld_lds16(g + row * ld + c * 8, lds + chunk * 512);
    }
}

// Fragment read from swizzled 64-pitch tile: 2-way LDS aliasing only (free, m136).
__device__ __forceinline__ bf16x8 read_frag_sw(const bf16_t* lds, int row, int cg)
{
    const int sw = cg ^ (row & 7);
    return *(const bf16x8*)(lds + row * 64 + sw * 8);
}

// ---------------- fp32 -> bf16 convert, 3 regions in one launch ----------------
// blocks [0,8192): x (16Mi elems); [8192,9728): w_qkv (3Mi); [9728,10240): w_out (1Mi)
__global__ __launch_bounds__(256) void cvt3_kernel(
    const float* __restrict__ x, bf16_t* __restrict__ xb,
    const float* __restrict__ wq, bf16_t* __restrict__ wqb,
    const float* __restrict__ wo, bf16_t* __restrict__ wob)
{
    const int bid = blockIdx.x;
    const float* src;
    bf16_t* dst;
    int base;
    if (bid < 8192)      { src = x;  dst = xb;  base = bid; }
    else if (bid < 9728) { src = wq; dst = wqb; base = bid - 8192; }
    else                 { src = wo; dst = wob; base = bid - 9728; }
    const size_t idx = ((size_t)base * 256 + threadIdx.x) * 8;
    f32x8 f = *(const f32x8*)(src + idx);
    bf16x8 v;
#pragma unroll
    for (int t = 0; t < 8; ++t) v[t] = (bf16_t)f[t];
    *(bf16x8*)(dst + idx) = v;
}

// ---------------- GEMM: C = A @ B^T, both bf16, fp32 accum ----------------
// Block 256 thr = 4 waves (2x2), tile 128x128, BK=64, 4x4 16x16x32 acc per wave.
// MODE 0: QKV epilogue (out0=Q, out1=KT, out2=VT, all bf16; KT/VT via coalescing LDS transpose).
// MODE 1: fp32 out + fp32 bias.
template <int MODE>
__global__ __launch_bounds__(256, 4) void gemm_bt_kernel(
    const bf16_t* __restrict__ A, const bf16_t* __restrict__ B, int K,
    void* __restrict__ out0, bf16_t* __restrict__ out1, bf16_t* __restrict__ out2,
    const float* __restrict__ bias)
{
    // 33KB: K-loop uses [0,16384) as As/Bs; MODE0 K/V epilogue reuses all of it as [128][TP_PITCH].
    __shared__ __align__(16) bf16_t smem[128 * TP_PITCH];
    bf16_t* As = smem;
    bf16_t* Bs = smem + 8192;
    const int tid = threadIdx.x;
    const int l = tid & 63, w = tid >> 6;
    const int wm = w >> 1, wn = w & 1;
    const int quad = l >> 4, r16 = l & 15;
    const int m0 = blockIdx.y * 128;
    const int n0 = blockIdx.x * 128;

    f32x4 acc[4][4];
#pragma unroll
    for (int i = 0; i < 4; ++i)
#pragma unroll
        for (int j = 0; j < 4; ++j) acc[i][j] = zf4();

    const bf16_t* Ab = A + (size_t)m0 * K;
    const bf16_t* Bb = B + (size_t)n0 * K;

    for (int k0 = 0; k0 < K; k0 += 64) {
        stage_async<128>(Ab + k0, K, As, tid);
        stage_async<128>(Bb + k0, K, Bs, tid);
        __syncthreads();
#pragma unroll
        for (int ks = 0; ks < 2; ++ks) {
            const int cg = ks * 4 + quad;
            bf16x8 af[4], bfr[4];
#pragma unroll
            for (int i = 0; i < 4; ++i) af[i] = read_frag_sw(As, wm * 64 + i * 16 + r16, cg);
#pragma unroll
            for (int j = 0; j < 4; ++j) bfr[j] = read_frag_sw(Bs, wn * 64 + j * 16 + r16, cg);
#pragma unroll
            for (int i = 0; i < 4; ++i)
#pragma unroll
                for (int j = 0; j < 4; ++j)
                    acc[i][j] = MFMA16(af[i], bfr[j], acc[i][j]);
        }
        __syncthreads();
    }

    // C/D layout (m89/m91-verified): col = lane&15, row = quad*4 + reg
    const float scale = 0.3535533905932738f;  // 64^-0.25
    if (MODE == 1) {
#pragma unroll
        for (int i = 0; i < 4; ++i) {
            const int mbase = m0 + wm * 64 + i * 16 + quad * 4;
#pragma unroll
            for (int j = 0; j < 4; ++j) {
                const int col = n0 + wn * 64 + j * 16 + r16;
                float* yp = (float*)out0;
                const float bb = bias[col];
#pragma unroll
                for (int r = 0; r < 4; ++r)
                    yp[(size_t)(mbase + r) * 1024 + col] = acc[i][j][r] + bb;
            }
        }
    } else {
        const int part = n0 >> 10;  // block-uniform: 0=q, 1=k, 2=v (n0 multiple of 128)
        if (part == 0) {
            // Q: [b,h,n,d], feat*scale; 32B-granule stores (unchanged path)
#pragma unroll
            for (int i = 0; i < 4; ++i) {
                const int mbase = m0 + wm * 64 + i * 16 + quad * 4;
#pragma unroll
                for (int j = 0; j < 4; ++j) {
                    const int col = n0 + wn * 64 + j * 16 + r16;
                    const int cc = col & 1023;
                    const int hh = (mbase >> 12) * 16 + (cc >> 6);
                    const int d = cc & 63;
                    const int ntok = mbase & 4095;
                    bf16_t* qp = (bf16_t*)out0 + ((size_t)hh * 4096 + ntok) * 64 + d;
#pragma unroll
                    for (int r = 0; r < 4; ++r)
                        qp[(size_t)r * 64] = (bf16_t)(feat(acc[i][j][r]) * scale);
                }
            }
        } else {
            // K/V -> transposed [b,h,d,n]: bounce tile through LDS [col][tok], then store
            // 128 rows x 256B contiguous (kills the 8B-stride-8KB RFO/write-amp).
#pragma unroll
            for (int i = 0; i < 4; ++i) {
                const int tokb = wm * 64 + i * 16 + quad * 4;  // local token 0..127 (+r)
#pragma unroll
                for (int j = 0; j < 4; ++j) {
                    const int colc = wn * 64 + j * 16 + r16;   // local col 0..127
                    bf16x4 pk;
#pragma unroll
                    for (int r = 0; r < 4; ++r) {
                        float v = acc[i][j][r];
                        if (part == 1) v = feat(v) * scale;
                        pk[r] = (bf16_t)v;
                    }
                    *(bf16x4*)(smem + colc * TP_PITCH + tokb) = pk;
                }
            }
            __syncthreads();
            bf16_t* basep = (part == 1 ? out1 : out2);
            const int b = m0 >> 12, tokb = m0 & 4095;
            const int row = tid >> 1, off = (tid & 1) * 64;
            const int cc = (n0 & 1023) + row;
            bf16_t* dst = basep + ((size_t)(b * 16 + (cc >> 6)) * 64 + (cc & 63)) * 4096 + tokb + off;
            const bf16_t* srcl = smem + row * TP_PITCH + off;
#pragma unroll
            for (int c8 = 0; c8 < 8; ++c8)
                *(bf16x8*)(dst + c8 * 8) = *(const bf16x8*)(srcl + c8 * 8);
        }
    }
}

// kv partials + ksum partials: block = (head hh, K-split ksp 0..15). Wave w owns e-rows
// [w*16, w*16+16). LDS-free / barrier-free: frags loaded global->reg directly. Lanes of a quad
// read adjacent 16B windows of the same row -> full 64B line utilization; K-frag 4x wave
// redundancy is L2-absorbed. No __syncthreads => all 40 loads pipeline freely.
// kvp[hh][ksp][e][d] = sum_n v[n,e] k[n,d]  (A=V-frag, B=K-frag -> C[e][d] directly).
// ksp[hh][ksp][d]    = sum_n k[n,d]         (wave 0 only: A=ones -> every C row = column sums).
__global__ __launch_bounds__(256) void kv_partial_kernel(
    const bf16_t* __restrict__ KT, const bf16_t* __restrict__ VT,
    float* __restrict__ kvp, float* __restrict__ ksp_out)
{
    const int tid = threadIdx.x;
    const int l = tid & 63, w = tid >> 6;
    const int quad = l >> 4, r16 = l & 15;
    const int hh = blockIdx.x;   // 0..63 (b*16+h)
    const int ksp = blockIdx.y;  // 0..15 (256-token slice)
    const bf16_t* kb = KT + (size_t)hh * 64 * 4096 + ksp * 256 + quad * 8;
    const bf16_t* vb = VT + (size_t)hh * 64 * 4096 + ksp * 256 + quad * 8;
    const bf16_t* vrow = vb + (size_t)(w * 16 + r16) * 4096;

    bf16x8 ones;
#pragma unroll
    for (int t = 0; t < 8; ++t) ones[t] = (bf16_t)1.0f;

    f32x4 acc[4], accks[4];
#pragma unroll
    for (int j = 0; j < 4; ++j) { acc[j] = zf4(); accks[j] = zf4(); }

#pragma unroll
    for (int kk = 0; kk < 8; ++kk) {  // 8 windows of 32 tokens; frag k-elem = win + quad*8 + t
        const int off = kk * 32;
        const bf16x8 af = *(const bf16x8*)(vrow + off);           // A = V (m-index = e)
        bf16x8 bk[4];
#pragma unroll
        for (int j = 0; j < 4; ++j)                               // B = K (n-index = d)
            bk[j] = *(const bf16x8*)(kb + (size_t)(j * 16 + r16) * 4096 + off);
#pragma unroll
        for (int j = 0; j < 4; ++j) acc[j] = MFMA16(af, bk[j], acc[j]);
        if (w == 0) {
#pragma unroll
            for (int j = 0; j < 4; ++j) accks[j] = MFMA16(ones, bk[j], accks[j]);
        }
    }

    float* ob = kvp + (size_t)(hh * 16 + ksp) * 4096;
    const int ebase = w * 16 + quad * 4;
#pragma unroll
    for (int j = 0; j < 4; ++j)
#pragma unroll
        for (int r = 0; r < 4; ++r)
            ob[(ebase + r) * 64 + j * 16 + r16] = acc[j][r];

    if (w == 0 && quad == 0) {
        float* kso = ksp_out + (size_t)(hh * 16 + ksp) * 64;
#pragma unroll
        for (int j = 0; j < 4; ++j) kso[j * 16 + r16] = accks[j][0];  // all C rows identical
    }
}

// att = (q @ kv) / (q . ksum + eps); block = (head, 256-token tile); wave = 64 tokens.
// Preamble reduces the 16 fp32 K-split partials (kvp/ksp, L2-resident) directly into LDS.
__global__ __launch_bounds__(256, 2) void attn_out_kernel(
    const bf16_t* __restrict__ Q, const float* __restrict__ kvp, const float* __restrict__ ksp,
    bf16_t* __restrict__ att)
{
    __shared__ __align__(16) bf16_t kvT[64 * LDS_PITCH];  // [e][d]
    __shared__ __align__(16) bf16_t ksb[64];
    const int tid = threadIdx.x;
    const int l = tid & 63, w = tid >> 6;
    const int quad = l >> 4, r16 = l & 15;
    const int hh = blockIdx.x;
    const int b = hh >> 4, h = hh & 15;
    const int mt = blockIdx.y;  // 0..15

    {   // preamble: reduce kvp[hh][0..16][e][d] -> kvT (bf16, padded); ksp -> ksb
        const int e = tid >> 2, d0 = (tid & 3) * 16;
        const float* kvph = kvp + (size_t)hh * 16 * 4096 + e * 64 + d0;
        f32x4 s[4];
#pragma unroll
        for (int q4 = 0; q4 < 4; ++q4) s[q4] = *(const f32x4*)(kvph + q4 * 4);
#pragma unroll
        for (int p = 1; p < 16; ++p)
#pragma unroll
            for (int q4 = 0; q4 < 4; ++q4) s[q4] += *(const f32x4*)(kvph + p * 4096 + q4 * 4);
        bf16x8 o0, o1;
#pragma unroll
        for (int r = 0; r < 4; ++r) {
            o0[r] = (bf16_t)s[0][r]; o0[4 + r] = (bf16_t)s[1][r];
            o1[r] = (bf16_t)s[2][r]; o1[4 + r] = (bf16_t)s[3][r];
        }
        *(bf16x8*)(kvT + e * LDS_PITCH + d0)     = o0;
        *(bf16x8*)(kvT + e * LDS_PITCH + d0 + 8) = o1;
        if (tid < 64) {
            const float* kp = ksp + (size_t)hh * 16 * 64 + tid;
            float ks = 0.f;
#pragma unroll
            for (int p = 0; p < 16; ++p) ks += kp[p * 64];
            ksb[tid] = (bf16_t)ks;
        }
    }
    __syncthreads();

    f32x4 acc[4][4];
    f32x4 dacc[4];
#pragma unroll
    for (int i = 0; i < 4; ++i) {
        dacc[i] = zf4();
#pragma unroll
        for (int j = 0; j < 4; ++j) acc[i][j] = zf4();
    }

    const int m0w = mt * 256 + w * 64;
    const bf16_t* qb = Q + (size_t)hh * 4096 * 64;
#pragma unroll
    for (int ks = 0; ks < 2; ++ks) {
        bf16x8 kf = *(const bf16x8*)(ksb + ks * 32 + quad * 8);
        if (r16 != 0) {
#pragma unroll
            for (int t = 0; t < 8; ++t) kf[t] = (bf16_t)0.f;
        }
        bf16x8 bfr[4];
#pragma unroll
        for (int j = 0; j < 4; ++j)
            bfr[j] = *(const bf16x8*)(kvT + (j * 16 + r16) * LDS_PITCH + ks * 32 + quad * 8);
#pragma unroll
        for (int i = 0; i < 4; ++i) {
            const bf16_t* qp = qb + (size_t)(m0w + i * 16 + r16) * 64 + ks * 32 + quad * 8;
            const bf16x8 af = *(const bf16x8*)qp;
            dacc[i] = MFMA16(af, kf, dacc[i]);
#pragma unroll
            for (int j = 0; j < 4; ++j) acc[i][j] = MFMA16(af, bfr[j], acc[i][j]);
        }
    }

#pragma unroll
    for (int i = 0; i < 4; ++i) {
        float den[4];
#pragma unroll
        for (int r = 0; r < 4; ++r)
            den[r] = __shfl(dacc[i][r], l & 48) + 1e-6f;  // quad's col-0 lane holds my rows' denom
#pragma unroll
        for (int j = 0; j < 4; ++j) {
            const size_t colb = (size_t)h * 64 + j * 16 + r16;
#pragma unroll
            for (int r = 0; r < 4; ++r) {
                const int ntok = m0w + i * 16 + quad * 4 + r;
                att[((size_t)b * 4096 + ntok) * 1024 + colb] = (bf16_t)(acc[i][j][r] / den[r]);
            }
        }
    }
}

extern "C" void kernel_launch(void* const* d_in, const int* in_sizes, int n_in,
                              void* d_out, int out_size, void* d_ws, size_t ws_size,
                              hipStream_t stream)
{
    const float* x    = (const float*)d_in[0];  // [4,4096,1024] fp32
    const float* wqkv = (const float*)d_in[1];  // [3072,1024] fp32
    const float* wout = (const float*)d_in[2];  // [1024,1024] fp32
    const float* bout = (const float*)d_in[3];  // [1024] fp32
    float* y = (float*)d_out;                   // [4,4096,1024] fp32

    char* ws = (char*)d_ws;
    bf16_t* xb    = (bf16_t*)ws;                          // 32 MiB  [16384,1024]
    bf16_t* wqkvb = (bf16_t*)(ws + (size_t)32 * 1048576); //  6 MiB  [3072,1024]
    bf16_t* woutb = (bf16_t*)(ws + (size_t)38 * 1048576); //  2 MiB  [1024,1024]
    bf16_t* Q     = (bf16_t*)(ws + (size_t)40 * 1048576); // 32 MiB  [b,h,n,d]
    bf16_t* KT    = (bf16_t*)(ws + (size_t)72 * 1048576); // 32 MiB  [b,h,d,n]
    bf16_t* VT    = (bf16_t*)(ws + (size_t)104 * 1048576);// 32 MiB  [b,h,d,n]  (end: 136 MiB)
    // aliases into xb region (xb dead after gemm<0>):
    float* kvp    = (float*)ws;                           // 16 MiB  [hh][16][e][d]
    float* ksp    = (float*)(ws + (size_t)16 * 1048576);  // 256 KiB [hh][16][d]
    bf16_t* att   = KT;                                   // KT dead after kv_partial

    cvt3_kernel<<<10240, 256, 0, stream>>>(x, xb, wqkv, wqkvb, wout, woutb);

    gemm_bt_kernel<0><<<dim3(24, 128), 256, 0, stream>>>(xb, wqkvb, 1024, Q, KT, VT, nullptr);
    kv_partial_kernel<<<dim3(64, 16), 256, 0, stream>>>(KT, VT, kvp, ksp);
    attn_out_kernel<<<dim3(64, 16), 256, 0, stream>>>(Q, kvp, ksp, att);
    gemm_bt_kernel<1><<<dim3(8, 128), 256, 0, stream>>>(att, woutb, 1024, y, nullptr, nullptr, bout);
}

// Round 17
// 330.676 us; speedup vs baseline: 1.0656x; 1.0656x over previous
//
#include <hip/hip_runtime.h>
#include <hip/hip_bf16.h>
#include <cmath>

// LinearAttention: x[4,4096,1024] fp32 -> qkv -> elu+1 linear attention (16 heads, d=64) -> out proj.
// I/O fp32; internal bf16 MFMA w/ fp32 accum.
// Round 16 (resubmit; prior bench was GPUAcquisitionTimeout, kernel never ran):
// BANK the best-measured configuration (R9, 327.1us) verbatim. Session scorecard:
// R0 332.6 / R4 324.8 / R9 327.1 / R10 331.4 / R12 336.3 / R15 352.4 -- six structural variants
// pinned at ~327+-5; all further-restructuring attempts (8-phase x3, occupancy, kvfix fusion,
// barrier-free kv_partial, XCD swizzle, store coalescing) were neutral-to-harmful. Per the
// pre-committed stopping rule, this banks the proven config: 128-tile/4-wave GEMMs (118us
// gemm<0>, 873 TF), LDS-staged kv_partial ksp=8, kvfix, attn_out, merged cvt3.
// Pipeline:
//   0) cvt3: x->xb, w_qkv->wqkvb, w_out->woutb (bf16)
//   1) gemm_bt<0>: qkv = xb @ wqkvb^T; epilogue q->feat*scale->Q[b,h,n,d], k->KT[b,h,d,n], v->VT
//   2) kv_partial: kvp[hh][ksp][e][d] = sum_n v[n,e] k[n,d]; ksp[hh][ksp][d] = sum_n k[n,d]  (ksp=8)
//   3) kvfix: kvb[hh][e][d] (bf16) = sum_ksp kvp; ksumb[hh][d] (bf16) = sum_ksp ksp
//   4) attn_out: att = (q @ kv) / (q . ksum + eps), denom via extra MFMA column
//   5) gemm_bt<1>: y = att @ woutb^T + b_out (fp32 out)

typedef __bf16 bf16_t;
typedef __attribute__((ext_vector_type(8))) __bf16 bf16x8;
typedef __attribute__((ext_vector_type(4))) __bf16 bf16x4;
typedef __attribute__((ext_vector_type(4))) float f32x4;
typedef __attribute__((ext_vector_type(8))) float f32x8;

#define MFMA16(a, b, c) __builtin_amdgcn_mfma_f32_16x16x32_bf16((a), (b), (c), 0, 0, 0)

#define LDS_PITCH 72  // padded pitch for the simple-staging (non-GEMM) kernels

__device__ __forceinline__ f32x4 zf4() { f32x4 z; z[0] = 0.f; z[1] = 0.f; z[2] = 0.f; z[3] = 0.f; return z; }

__device__ __forceinline__ float feat(float x) { return x > 0.f ? x + 1.f : expf(x); }

// ---------------- async staging (GEMM path) ----------------
__device__ __forceinline__ void gld_lds16(const bf16_t* src, bf16_t* dst)
{
    __builtin_amdgcn_global_load_lds(
        (__attribute__((address_space(1))) void*)const_cast<bf16_t*>(src),
        (__attribute__((address_space(3))) void*)dst, 16, 0, 0);
}

// Stage NR x 64 bf16 tile (row stride ld) into LDS, XOR-swizzled, via global_load_lds.
// LDS granule (row, sw) holds global granule (row, sw^(row&7)); readers apply the same XOR.
template <int NR>
__device__ __forceinline__ void stage_async(const bf16_t* g, int ld, bf16_t* lds, int tid)
{
    const int w = tid >> 6, l = tid & 63;
    constexpr int CALLS = NR >> 5;  // per-wave calls; each call = 64 granules = 8 rows
#pragma unroll
    for (int p = 0; p < CALLS; ++p) {
        const int chunk = w * CALLS + p;         // wave-uniform
        const int gidx = chunk * 64 + l;
        const int row = gidx >> 3;
        const int cp = gidx & 7;
        const int c = cp ^ (row & 7);
        gld_lds16(g + row * ld + c * 8, lds + chunk * 512);
    }
}

// Fragment read from swizzled 64-pitch tile: 2-way LDS aliasing only (free, m136).
__device__ __forceinline__ bf16x8 read_frag_sw(const bf16_t* lds, int row, int cg)
{
    const int sw = cg ^ (row & 7);
    return *(const bf16x8*)(lds + row * 64 + sw * 8);
}

// ---------------- simple staging (middle kernels) ----------------
template <int NR>
__device__ __forceinline__ void stage_bf16(const bf16_t* g, int ld, bf16_t* lds, int tid)
{
#pragma unroll
    for (int p = 0; p < NR * 8 / 256; ++p) {
        const int gidx = p * 256 + tid;
        const int row = gidx >> 3;
        const int cp = gidx & 7;
        *(bf16x8*)(lds + row * LDS_PITCH + cp * 8) = *(const bf16x8*)(g + row * ld + cp * 8);
    }
}

__device__ __forceinline__ bf16x8 read_frag(const bf16_t* lds, int row, int cg)
{
    return *(const bf16x8*)(lds + row * LDS_PITCH + cg * 8);
}

// ---------------- fp32 -> bf16 convert, 3 regions in one launch ----------------
// blocks [0,8192): x (16Mi elems); [8192,9728): w_qkv (3Mi); [9728,10240): w_out (1Mi)
__global__ __launch_bounds__(256) void cvt3_kernel(
    const float* __restrict__ x, bf16_t* __restrict__ xb,
    const float* __restrict__ wq, bf16_t* __restrict__ wqb,
    const float* __restrict__ wo, bf16_t* __restrict__ wob)
{
    const int bid = blockIdx.x;
    const float* src;
    bf16_t* dst;
    int base;
    if (bid < 8192)      { src = x;  dst = xb;  base = bid; }
    else if (bid < 9728) { src = wq; dst = wqb; base = bid - 8192; }
    else                 { src = wo; dst = wob; base = bid - 9728; }
    const size_t idx = ((size_t)base * 256 + threadIdx.x) * 8;
    f32x8 f = *(const f32x8*)(src + idx);
    bf16x8 v;
#pragma unroll
    for (int t = 0; t < 8; ++t) v[t] = (bf16_t)f[t];
    *(bf16x8*)(dst + idx) = v;
}

// ---------------- GEMM: C = A @ B^T, both bf16, fp32 accum ----------------
// Block 256 thr = 4 waves (2x2), tile 128x128, BK=64, 4x4 16x16x32 acc per wave.
// MODE 0: QKV epilogue (out0=Q, out1=KT, out2=VT, all bf16). MODE 1: fp32 out + fp32 bias.
template <int MODE>
__global__ __launch_bounds__(256, 3) void gemm_bt_kernel(
    const bf16_t* __restrict__ A, const bf16_t* __restrict__ B, int K,
    void* __restrict__ out0, bf16_t* __restrict__ out1, bf16_t* __restrict__ out2,
    const float* __restrict__ bias)
{
    __shared__ __align__(16) bf16_t As[128 * 64];
    __shared__ __align__(16) bf16_t Bs[128 * 64];
    const int tid = threadIdx.x;
    const int l = tid & 63, w = tid >> 6;
    const int wm = w >> 1, wn = w & 1;
    const int quad = l >> 4, r16 = l & 15;
    const int m0 = blockIdx.y * 128;
    const int n0 = blockIdx.x * 128;

    f32x4 acc[4][4];
#pragma unroll
    for (int i = 0; i < 4; ++i)
#pragma unroll
        for (int j = 0; j < 4; ++j) acc[i][j] = zf4();

    const bf16_t* Ab = A + (size_t)m0 * K;
    const bf16_t* Bb = B + (size_t)n0 * K;

    for (int k0 = 0; k0 < K; k0 += 64) {
        stage_async<128>(Ab + k0, K, As, tid);
        stage_async<128>(Bb + k0, K, Bs, tid);
        __syncthreads();
#pragma unroll
        for (int ks = 0; ks < 2; ++ks) {
            const int cg = ks * 4 + quad;
            bf16x8 af[4], bfr[4];
#pragma unroll
            for (int i = 0; i < 4; ++i) af[i] = read_frag_sw(As, wm * 64 + i * 16 + r16, cg);
#pragma unroll
            for (int j = 0; j < 4; ++j) bfr[j] = read_frag_sw(Bs, wn * 64 + j * 16 + r16, cg);
#pragma unroll
            for (int i = 0; i < 4; ++i)
#pragma unroll
                for (int j = 0; j < 4; ++j)
                    acc[i][j] = MFMA16(af[i], bfr[j], acc[i][j]);
        }
        __syncthreads();
    }

    // C/D layout (m89/m91-verified): col = lane&15, row = quad*4 + reg
    const float scale = 0.3535533905932738f;  // 64^-0.25
#pragma unroll
    for (int i = 0; i < 4; ++i) {
        const int mbase = m0 + wm * 64 + i * 16 + quad * 4;
#pragma unroll
        for (int j = 0; j < 4; ++j) {
            const int col = n0 + wn * 64 + j * 16 + r16;
            if (MODE == 1) {
                float* yp = (float*)out0;
                const float bb = bias[col];
#pragma unroll
                for (int r = 0; r < 4; ++r)
                    yp[(size_t)(mbase + r) * 1024 + col] = acc[i][j][r] + bb;
            } else {
                const int part = col >> 10;      // 0=q, 1=k, 2=v
                const int cc = col & 1023;
                const int hh = (mbase >> 12) * 16 + (cc >> 6);  // b*16 + h
                const int d = cc & 63;
                const int ntok = mbase & 4095;
                if (part == 0) {
                    bf16_t* qp = (bf16_t*)out0 + ((size_t)hh * 4096 + ntok) * 64 + d;
#pragma unroll
                    for (int r = 0; r < 4; ++r)
                        qp[(size_t)r * 64] = (bf16_t)(feat(acc[i][j][r]) * scale);
                } else {
                    // transposed [b,h,d,n]; 4 consecutive tokens -> 8B vector store
                    bf16_t* tp = (part == 1 ? out1 : out2) + ((size_t)hh * 64 + d) * 4096 + ntok;
                    bf16x4 pk;
#pragma unroll
                    for (int r = 0; r < 4; ++r) {
                        float v = acc[i][j][r];
                        if (part == 1) v = feat(v) * scale;
                        pk[r] = (bf16_t)v;
                    }
                    *(bf16x4*)tp = pk;
                }
            }
        }
    }
}

// kv partials + ksum partials: block = (head hh, K-split ksp 0..7). Wave w owns e-rows [w*16,w*16+16).
// kvp[hh][ksp][e][d] = sum_n v[n,e] k[n,d]  (A=V-frag, B=K-frag -> C[e][d] directly).
// ksp[hh][ksp][d]    = sum_n k[n,d]         (wave 0 only: A=ones -> every C row = column sums).
__global__ __launch_bounds__(256, 2) void kv_partial_kernel(
    const bf16_t* __restrict__ KT, const bf16_t* __restrict__ VT,
    float* __restrict__ kvp, float* __restrict__ ksp_out)
{
    __shared__ __align__(16) bf16_t Ks[64 * LDS_PITCH];
    __shared__ __align__(16) bf16_t Vs[64 * LDS_PITCH];
    const int tid = threadIdx.x;
    const int l = tid & 63, w = tid >> 6;
    const int quad = l >> 4, r16 = l & 15;
    const int hh = blockIdx.x;   // 0..63 (b*16+h)
    const int ksp = blockIdx.y;  // 0..7
    const bf16_t* kb = KT + (size_t)hh * 64 * 4096 + ksp * 512;
    const bf16_t* vb = VT + (size_t)hh * 64 * 4096 + ksp * 512;

    bf16x8 ones;
#pragma unroll
    for (int t = 0; t < 8; ++t) ones[t] = (bf16_t)1.0f;

    f32x4 acc[4], accks[4];
#pragma unroll
    for (int j = 0; j < 4; ++j) { acc[j] = zf4(); accks[j] = zf4(); }

    for (int k0 = 0; k0 < 512; k0 += 64) {
        stage_bf16<64>(kb + k0, 4096, Ks, tid);
        stage_bf16<64>(vb + k0, 4096, Vs, tid);
        __syncthreads();
#pragma unroll
        for (int ks = 0; ks < 2; ++ks) {
            const int cg = ks * 4 + quad;
            bf16x8 af = read_frag(Vs, w * 16 + r16, cg);  // A = V (m-index = e)
            bf16x8 bk[4];
#pragma unroll
            for (int j = 0; j < 4; ++j) bk[j] = read_frag(Ks, j * 16 + r16, cg);  // B = K (n-index = d)
#pragma unroll
            for (int j = 0; j < 4; ++j) acc[j] = MFMA16(af, bk[j], acc[j]);
            if (w == 0) {
#pragma unroll
                for (int j = 0; j < 4; ++j) accks[j] = MFMA16(ones, bk[j], accks[j]);
            }
        }
        __syncthreads();
    }

    float* ob = kvp + (size_t)(hh * 8 + ksp) * 4096;
    const int ebase = w * 16 + quad * 4;
#pragma unroll
    for (int j = 0; j < 4; ++j)
#pragma unroll
        for (int r = 0; r < 4; ++r)
            ob[(ebase + r) * 64 + j * 16 + r16] = acc[j][r];

    if (w == 0 && quad == 0) {
        float* kso = ksp_out + (size_t)(hh * 8 + ksp) * 64;
#pragma unroll
        for (int j = 0; j < 4; ++j) kso[j * 16 + r16] = accks[j][0];  // all C rows identical
    }
}

// Reduce 8 K-split partials once: kvb[hh][e][d] bf16, ksumb[hh][d] bf16.
// Block = (hh, chunk c of 1024 floats); 256 thr x f32x4.
__global__ __launch_bounds__(256) void kvfix_kernel(
    const float* __restrict__ kvp, const float* __restrict__ ksp,
    bf16_t* __restrict__ kvb, bf16_t* __restrict__ ksumb)
{
    const int hh = blockIdx.x, c = blockIdx.y, t = threadIdx.x;
    const float* base = kvp + (size_t)hh * 8 * 4096 + c * 1024 + t * 4;
    f32x4 s = *(const f32x4*)base;
#pragma unroll
    for (int p = 1; p < 8; ++p) s += *(const f32x4*)(base + (size_t)p * 4096);
    bf16x4 o;
#pragma unroll
    for (int r = 0; r < 4; ++r) o[r] = (bf16_t)s[r];
    *(bf16x4*)(kvb + (size_t)hh * 4096 + c * 1024 + t * 4) = o;

    if (c == 0 && t < 64) {
        const float* kb = ksp + (size_t)hh * 8 * 64 + t;
        float ks = 0.f;
#pragma unroll
        for (int p = 0; p < 8; ++p) ks += kb[(size_t)p * 64];
        ksumb[(size_t)hh * 64 + t] = (bf16_t)ks;
    }
}

// att = (q @ kv) / (q . ksum + eps); block = (head, 256-token tile); wave = 64 tokens.
__global__ __launch_bounds__(256, 2) void attn_out_kernel(
    const bf16_t* __restrict__ Q, const bf16_t* __restrict__ kvb, const bf16_t* __restrict__ ksumb,
    bf16_t* __restrict__ att)
{
    __shared__ __align__(16) bf16_t kvT[64 * LDS_PITCH];  // [e][d]
    __shared__ __align__(16) bf16_t ksb[64];
    const int tid = threadIdx.x;
    const int l = tid & 63, w = tid >> 6;
    const int quad = l >> 4, r16 = l & 15;
    const int hh = blockIdx.x;
    const int b = hh >> 4, h = hh & 15;
    const int mt = blockIdx.y;  // 0..15

    {   // coalesced preamble: kvb[hh] (8KB) -> padded LDS; ksumb -> ksb
        const int e = tid >> 2, d0 = (tid & 3) * 16;
        const bf16_t* kvbh = kvb + (size_t)hh * 4096;
        *(bf16x8*)(kvT + e * LDS_PITCH + d0)     = *(const bf16x8*)(kvbh + e * 64 + d0);
        *(bf16x8*)(kvT + e * LDS_PITCH + d0 + 8) = *(const bf16x8*)(kvbh + e * 64 + d0 + 8);
        if (tid < 64) ksb[tid] = ksumb[(size_t)hh * 64 + tid];
    }
    __syncthreads();

    f32x4 acc[4][4];
    f32x4 dacc[4];
#pragma unroll
    for (int i = 0; i < 4; ++i) {
        dacc[i] = zf4();
#pragma unroll
        for (int j = 0; j < 4; ++j) acc[i][j] = zf4();
    }

    const int m0w = mt * 256 + w * 64;
    const bf16_t* qb = Q + (size_t)hh * 4096 * 64;
#pragma unroll
    for (int ks = 0; ks < 2; ++ks) {
        bf16x8 kf = *(const bf16x8*)(ksb + ks * 32 + quad * 8);
        if (r16 != 0) {
#pragma unroll
            for (int t = 0; t < 8; ++t) kf[t] = (bf16_t)0.f;
        }
        bf16x8 bfr[4];
#pragma unroll
        for (int j = 0; j < 4; ++j)
            bfr[j] = *(const bf16x8*)(kvT + (j * 16 + r16) * LDS_PITCH + ks * 32 + quad * 8);
#pragma unroll
        for (int i = 0; i < 4; ++i) {
            const bf16_t* qp = qb + (size_t)(m0w + i * 16 + r16) * 64 + ks * 32 + quad * 8;
            const bf16x8 af = *(const bf16x8*)qp;
            dacc[i] = MFMA16(af, kf, dacc[i]);
#pragma unroll
            for (int j = 0; j < 4; ++j) acc[i][j] = MFMA16(af, bfr[j], acc[i][j]);
        }
    }

#pragma unroll
    for (int i = 0; i < 4; ++i) {
        float den[4];
#pragma unroll
        for (int r = 0; r < 4; ++r)
            den[r] = __shfl(dacc[i][r], l & 48) + 1e-6f;  // quad's col-0 lane holds my rows' denom
#pragma unroll
        for (int j = 0; j < 4; ++j) {
            const size_t colb = (size_t)h * 64 + j * 16 + r16;
#pragma unroll
            for (int r = 0; r < 4; ++r) {
                const int ntok = m0w + i * 16 + quad * 4 + r;
                att[((size_t)b * 4096 + ntok) * 1024 + colb] = (bf16_t)(acc[i][j][r] / den[r]);
            }
        }
    }
}

extern "C" void kernel_launch(void* const* d_in, const int* in_sizes, int n_in,
                              void* d_out, int out_size, void* d_ws, size_t ws_size,
                              hipStream_t stream)
{
    const float* x    = (const float*)d_in[0];  // [4,4096,1024] fp32
    const float* wqkv = (const float*)d_in[1];  // [3072,1024] fp32
    const float* wout = (const float*)d_in[2];  // [1024,1024] fp32
    const float* bout = (const float*)d_in[3];  // [1024] fp32
    float* y = (float*)d_out;                   // [4,4096,1024] fp32

    char* ws = (char*)d_ws;
    bf16_t* xb    = (bf16_t*)ws;                          // 32 MiB  [16384,1024]
    bf16_t* wqkvb = (bf16_t*)(ws + (size_t)32 * 1048576); //  6 MiB  [3072,1024]
    bf16_t* woutb = (bf16_t*)(ws + (size_t)38 * 1048576); //  2 MiB  [1024,1024]
    bf16_t* Q     = (bf16_t*)(ws + (size_t)40 * 1048576); // 32 MiB  [b,h,n,d]
    bf16_t* KT    = (bf16_t*)(ws + (size_t)72 * 1048576); // 32 MiB  [b,h,d,n]
    bf16_t* VT    = (bf16_t*)(ws + (size_t)104 * 1048576);// 32 MiB  [b,h,d,n]  (end: 136 MiB)
    // aliases into xb region (xb dead after gemm<0>):
    float* kvp    = (float*)ws;                           // 8 MiB   [hh][8][e][d]
    float* ksp    = (float*)(ws + (size_t)8 * 1048576);   // 128 KiB [hh][8][d]
    bf16_t* kvb   = (bf16_t*)(ws + (size_t)9 * 1048576);  // 512 KiB [hh][e][d]
    bf16_t* ksumb = (bf16_t*)(ws + (size_t)10 * 1048576); // 8 KiB   [hh][d]
    bf16_t* att   = KT;                                   // KT dead after kv_partial

    cvt3_kernel<<<10240, 256, 0, stream>>>(x, xb, wqkv, wqkvb, wout, woutb);

    gemm_bt_kernel<0><<<dim3(24, 128), 256, 0, stream>>>(xb, wqkvb, 1024, Q, KT, VT, nullptr);
    kv_partial_kernel<<<dim3(64, 8), 256, 0, stream>>>(KT, VT, kvp, ksp);
    kvfix_kernel<<<dim3(64, 4), 256, 0, stream>>>(kvp, ksp, kvb, ksumb);
    attn_out_kernel<<<dim3(64, 16), 256, 0, stream>>>(Q, kvb, ksumb, att);
    gemm_bt_kernel<1><<<dim3(8, 128), 256, 0, stream>>>(att, woutb, 1024, y, nullptr, nullptr, bout);
}